// Round 14
// baseline (116.911 us; speedup 1.0000x reference)
//
#include <hip/hip_runtime.h>

// N=1536 T=20 H=64 E=16 M=128
// Qf[j,k] (16x16-MFMA-frag-tile layout), P[j,k]: fp16 in d_ws; W2f:
// pre-fragmented W2 (16KB). out[i] = max_j relu( relu(Q[j]-P[i]) @ W2 + b2 )
//
// R16: software-pipelined drain, paid for with FREE registers. Six falsified
// structures all pin at matrix 35% / VALU 15% / 2 waves/SIMD; the invariants
// never attacked: (a) the per-tile drain (48 fmax + MFMA-latency wait) is a
// SERIAL end-of-tile burst and MFMA blocks its wave; (b) regs up to the 256
// cap are free at the 2-wave ceiling. So: two acc sets -- tile t MFMAs chain
// into ACC while tile t-1 drains in 3 slices BETWEEN ks-clusters (max3 form).
// To fit <=256: H-cols split across wave pairs (CT=2/wave, bfrag 32, acc
// 2x24) => ~215 live. Grid 512x4x2 = 4096 = two clean 2/SIMD passes (R10's
// 3072-ragged penalty avoided). Every tile drains unconditionally (other
// set pre-inited to -inf). Loads/byte-addressing = R13 proven scaffold.

#define NN 1536
#define HH 64
#define EE 16
#define MM 128
#define TT 20

#define NI 3
#define NIGRP (NN / NI)       // 512 i-groups
#define JSPLIT 4
#define CSPL 2                // H-column split across wave pairs
#define NTILE (96 / JSPLIT)   // 24 j-tiles of 16 per wave

typedef _Float16 half8 __attribute__((ext_vector_type(8)));
typedef float f32x4 __attribute__((ext_vector_type(4)));

// grid NN, block 128. Computes Qf (16x16 frag-tile layout), P, W2f,
// zero-inits out. (verified R6-R14)
__global__ __launch_bounds__(128) void precompute_kernel(
    const float* __restrict__ hidden, const float* __restrict__ gt,
    const float* __restrict__ We, const float* __restrict__ be,
    const float* __restrict__ W1, const float* __restrict__ b1,
    const float* __restrict__ W2,
    _Float16* __restrict__ Qf, _Float16* __restrict__ P,
    _Float16* __restrict__ W2f, float* __restrict__ out)
{
  const int j = blockIdx.x;
  const int m = threadIdx.x;
  const float* hrow = hidden + j * HH;
  float a0 = 0.f, a1 = 0.f;
  #pragma unroll 8
  for (int h = 0; h < HH; h += 2) {
    a0 = fmaf(hrow[h],     W1[h * MM + m],       a0);
    a1 = fmaf(hrow[h + 1], W1[(h + 1) * MM + m], a1);
  }
  const float a = a0 + a1;
  float ve0 = 0.f, ve1 = 0.f, cm = b1[m];
  #pragma unroll
  for (int e = 0; e < EE; ++e) {
    float w1e = W1[(HH + e) * MM + m];
    ve0 = fmaf(We[e], w1e, ve0);       // We[0][e]
    ve1 = fmaf(We[EE + e], w1e, ve1);  // We[1][e]
    cm  = fmaf(be[e], w1e, cm);
  }
  const float e0 = gt[j * (2 * TT) + 2 * (TT - 1)];
  const float e1 = gt[j * (2 * TT) + 2 * (TT - 1) + 1];
  const float p = fmaf(e0, ve0, e1 * ve1);
  P[j * MM + m] = (_Float16)p;

  const int jt = j >> 4;
  const int ks = m >> 5;
  const int ln = ((m >> 3) & 3) * 16 + (j & 15);
  const int jj = m & 7;
  Qf[(((jt * 4) + ks) * 64 + ln) * 8 + jj] = (_Float16)(a + p + cm);

  if (m < HH) out[j * HH + m] = 0.f;

  // blocks 0..7: pre-fragment W2 -> W2f (verified R8-R14).
  if (j < 8) {
    const int u = j * 128 + m;          // 0..1023
    const int ct = u >> 8;
    const int ksx = (u >> 6) & 3;
    const int l = u & 63;
    half8 w;
    #pragma unroll
    for (int t = 0; t < 8; ++t)
      w[t] = (_Float16)W2[(ksx * 32 + (l >> 4) * 8 + t) * HH + ct * 16 + (l & 15)];
    *(half8*)(W2f + (size_t)u * 8) = w;
  }
}

// grid NIGRP*JSPLIT*CSPL = 4096, block 64 (1 wave). Wave: i0..i0+2, 24
// j-tiles, 2 of 4 H-col groups. Pipelined: tile t MFMAs || tile t-1 drain.
__global__ __launch_bounds__(64, 2) void pairmlp_max_kernel(
    const _Float16* __restrict__ Qf, const _Float16* __restrict__ P,
    const _Float16* __restrict__ W2f, const float* __restrict__ b2,
    float* __restrict__ out)
{
  const int lane = threadIdx.x;
  const int quad = lane >> 4;
  const int lcol = lane & 15;
  const int ig = blockIdx.x % NIGRP;        // consecutive blocks: same js,cs
  const int rest = blockIdx.x / NIGRP;      // -> same Q tile stream (L2 reuse)
  const int js = rest & (JSPLIT - 1);
  const int cs = rest >> 2;                 // 0 or 1: H-col half
  const int i0 = ig * NI;

  // B fragments for this wave's 2 col-groups: 8 coalesced 16B loads
  half8 bfrag[2][4];
  {
    const half8* wf = (const half8*)W2f + lane;
    #pragma unroll
    for (int c = 0; c < 2; ++c)
      #pragma unroll
      for (int ks = 0; ks < 4; ++ks)
        bfrag[c][ks] = wf[((cs * 2 + c) * 4 + ks) * 64];
  }

  // P fragments for NI i's
  half8 pv[NI][4];
  #pragma unroll
  for (int ii = 0; ii < NI; ++ii) {
    const _Float16* prow = P + (i0 + ii) * MM + quad * 8;
    #pragma unroll
    for (int ks = 0; ks < 4; ++ks)
      pv[ii][ks] = *(const half8*)(prow + ks * 32);
  }

  float b2v[2];
  #pragma unroll
  for (int c = 0; c < 2; ++c) b2v[c] = b2[(cs * 2 + c) * 16 + lcol];

  float rmax[NI][2];
  #pragma unroll
  for (int ii = 0; ii < NI; ++ii)
    #pragma unroll
    for (int c = 0; c < 2; ++c) rmax[ii][c] = -3.0e38f;

  // byte base: tile jt at jt*4096, ks at +1024*ks, lane at +16*lane
  const char* qbytes = (const char*)Qf + (size_t)(js * NTILE) * 4096 + lane * 16;

  const half8 hz = 0;
  const f32x4 fz = {0.f, 0.f, 0.f, 0.f};
  const f32x4 fninf = {-3.0e38f, -3.0e38f, -3.0e38f, -3.0e38f};

  // two acc sets: cur is written this tile, oacc (prev tile) drains in
  // slices between ks-clusters (after ks=1,2,3: slice ii=ks-1).
  f32x4 accA[NI][2], accB[NI][2];
  #pragma unroll
  for (int ii = 0; ii < NI; ++ii)
    #pragma unroll
    for (int c = 0; c < 2; ++c) accB[ii][c] = fninf;  // first drain harmless

  auto tile = [&](f32x4 (&acc)[NI][2], f32x4 (&oacc)[NI][2], const half8 (&qt)[4]) {
    #pragma unroll
    for (int ks = 0; ks < 4; ++ks) {
      __builtin_amdgcn_s_setprio(1);
      #pragma unroll
      for (int ii = 0; ii < NI; ++ii) {
        half8 s = qt[ks] - pv[ii][ks];
        s = __builtin_elementwise_max(s, hz);
        if (ks == 0) {
          acc[ii][0] = __builtin_amdgcn_mfma_f32_16x16x32_f16(s, bfrag[0][0], fz, 0, 0, 0);
          acc[ii][1] = __builtin_amdgcn_mfma_f32_16x16x32_f16(s, bfrag[1][0], fz, 0, 0, 0);
        } else {
          acc[ii][0] = __builtin_amdgcn_mfma_f32_16x16x32_f16(s, bfrag[0][ks], acc[ii][0], 0, 0, 0);
          acc[ii][1] = __builtin_amdgcn_mfma_f32_16x16x32_f16(s, bfrag[1][ks], acc[ii][1], 0, 0, 0);
        }
      }
      __builtin_amdgcn_s_setprio(0);
      // drain slice of the PREVIOUS tile's accs (max3-friendly, 4 ops/acc->2)
      if (ks >= 1) {
        const int di = ks - 1;
        #pragma unroll
        for (int c = 0; c < 2; ++c) {
          const float t3 = fmaxf(fmaxf(oacc[di][c][0], oacc[di][c][1]), oacc[di][c][2]);
          rmax[di][c] = fmaxf(fmaxf(t3, oacc[di][c][3]), rmax[di][c]);
        }
      }
    }
  };

  half8 qc[4], qn[4];
  const char* qp = qbytes;

  // prime qc from tile 0
  #pragma unroll
  for (int ks = 0; ks < 4; ++ks)
    qc[ks] = *(const half8*)(qp + ks * 1024);

  for (int t = 0; t < NTILE; t += 2) {
    // prefetch tile t+1 (always exists: NTILE even)
    #pragma unroll
    for (int ks = 0; ks < 4; ++ks)
      qn[ks] = *(const half8*)(qp + 4096 + ks * 1024);
    tile(accA, accB, qc);   // tile t   -> accA; drains accB (tile t-1)

    // prefetch tile t+2 (dummy base reload on last pair; unused)
    const char* q2 = (t + 2 < NTILE) ? (qp + 8192) : qbytes;
    #pragma unroll
    for (int ks = 0; ks < 4; ++ks)
      qc[ks] = *(const half8*)(q2 + ks * 1024);
    tile(accB, accA, qn);   // tile t+1 -> accB; drains accA (tile t)

    qp += 8192;
  }

  // final drain: accB holds the last tile
  #pragma unroll
  for (int ii = 0; ii < NI; ++ii)
    #pragma unroll
    for (int c = 0; c < 2; ++c) {
      const float t3 = fmaxf(fmaxf(accB[ii][c][0], accB[ii][c][1]), accB[ii][c][2]);
      rmax[ii][c] = fmaxf(fmaxf(t3, accB[ii][c][3]), rmax[ii][c]);
    }

  // combine quad-groups (different j rows, same col), then atomic max.
  #pragma unroll
  for (int ii = 0; ii < NI; ++ii)
    #pragma unroll
    for (int c = 0; c < 2; ++c) {
      float v = rmax[ii][c];
      v = fmaxf(v, __shfl_xor(v, 16, 64));
      v = fmaxf(v, __shfl_xor(v, 32, 64));
      v = fmaxf(v + b2v[c], 0.f);
      if (quad == 0)
        atomicMax((unsigned*)(out + (i0 + ii) * HH + (cs * 2 + c) * 16 + lcol),
                  __float_as_uint(v));
    }
}

extern "C" void kernel_launch(void* const* d_in, const int* in_sizes, int n_in,
                              void* d_out, int out_size, void* d_ws, size_t ws_size,
                              hipStream_t stream) {
  const float* hidden = (const float*)d_in[0];
  const float* gt     = (const float*)d_in[1];
  const float* We     = (const float*)d_in[2];
  const float* be     = (const float*)d_in[3];
  const float* W1     = (const float*)d_in[4];
  const float* b1     = (const float*)d_in[5];
  const float* W2     = (const float*)d_in[6];
  const float* b2     = (const float*)d_in[7];
  float* out = (float*)d_out;

  _Float16* Qf  = (_Float16*)d_ws;     // NN*MM fp16 (384KB), frag-tile layout
  _Float16* Ph  = Qf + NN * MM;        // NN*MM fp16 (384KB)
  _Float16* W2f = Ph + NN * MM;        // 4*4*64*8 fp16 (16KB), frag layout

  precompute_kernel<<<NN, 128, 0, stream>>>(hidden, gt, We, be, W1, b1, W2, Qf, Ph, W2f, out);
  pairmlp_max_kernel<<<NIGRP * JSPLIT * CSPL, 64, 0, stream>>>(Qf, Ph, W2f, b2, out);
}